// Round 13
// baseline (189.832 us; speedup 1.0000x reference)
//
#include <hip/hip_runtime.h>

#define NB 64
#define NN 256
#define IND 7
#define HIDD 64
#define OUTD 32
#define EPG 8192
#define ETOT 524288
#define DCAP 96       // fixed CSR bin per dst (mean deg 33, P(>95)~1e-18)

typedef _Float16 f16;
typedef f16 f16x2 __attribute__((ext_vector_type(2)));
typedef f16 f16x4 __attribute__((ext_vector_type(4)));
typedef f16 f16x8 __attribute__((ext_vector_type(8)));
typedef float f32x4 __attribute__((ext_vector_type(4)));

// ---------------- block reductions for 16-wave blocks ----------------
__device__ __forceinline__ float bsum16(float v, float* rb){
#pragma unroll
  for (int o = 32; o > 0; o >>= 1) v += __shfl_xor(v, o, 64);
  __syncthreads();
  if ((threadIdx.x & 63) == 0) rb[threadIdx.x >> 6] = v;
  __syncthreads();
  float s = 0.f;
#pragma unroll
  for (int i = 0; i < 16; i++) s += rb[i];
  return s;
}
__device__ __forceinline__ float bmin16(float v, float* rb){
#pragma unroll
  for (int o = 32; o > 0; o >>= 1) v = fminf(v, __shfl_xor(v, o, 64));
  __syncthreads();
  if ((threadIdx.x & 63) == 0) rb[threadIdx.x >> 6] = v;
  __syncthreads();
  float s = rb[0];
#pragma unroll
  for (int i = 1; i < 16; i++) s = fminf(s, rb[i]);
  return s;
}
__device__ __forceinline__ float bmax16(float v, float* rb){
#pragma unroll
  for (int o = 32; o > 0; o >>= 1) v = fmaxf(v, __shfl_xor(v, o, 64));
  __syncthreads();
  if ((threadIdx.x & 63) == 0) rb[threadIdx.x >> 6] = v;
  __syncthreads();
  float s = rb[0];
#pragma unroll
  for (int i = 1; i < 16; i++) s = fmaxf(s, rb[i]);
  return s;
}

__device__ __forceinline__ f16x2 lrelu2(f16x2 s){
  const f16x2 k = {(f16)0.2f, (f16)0.2f};
  return __builtin_elementwise_max(s, s * k);
}
__device__ __forceinline__ f16x2 shfl_h2(f16x2 v, int lane){
  int i = __builtin_bit_cast(int, v);
  i = __shfl(i, lane, 64);
  return __builtin_bit_cast(f16x2, i);
}

// ---------------- GAT layer 1 + single-pass fixed-bin CSR ----------------
// grid 512, XCD-swizzled: gs = bid&127, quarter = bid>>7. 8 thr/dst.
// CSR: fixed 96-entry bin per dst, built in ONE atomic pass (no count/scan).
// xl_s rows use an XOR chunk swizzle (phys = c ^ ((row>>3)&7)) to kill the
// 4-way write conflicts of the 144B row stride. exp fused into score loop.
__global__ __launch_bounds__(512, 4) void gat1(
    const float* __restrict__ x1, const float* __restrict__ x2,
    const int* __restrict__ e1, const int* __restrict__ e2,
    const float* __restrict__ Wl, const float* __restrict__ Wr,
    const float* __restrict__ bl, const float* __restrict__ br,
    const float* __restrict__ att, const float* __restrict__ bias,
    f16* __restrict__ hmid,
    int* __restrict__ meta, unsigned char* __restrict__ srcs)
{
  __shared__ __align__(16) f16 xl_s[256 * 72];     // rows 144B, chunk-swizzled
  __shared__ f16 sc_h[64 * DCAP];                  // softmax weights (f16)
  __shared__ unsigned int src_su[64 * DCAP / 4];
  __shared__ int deg_s[64];
  __shared__ unsigned char perm[64];
  unsigned char* src_s = (unsigned char*)src_su;

  const int bid = blockIdx.x;
  const int gs = bid & 127, lo = (bid >> 7) * 64;
  const int side = gs >> 6, g = gs & 63;
  const float* x = side ? x2 : x1;
  const int* eb = side ? e2 : e1;
  const int* es = eb + g * EPG;
  const int* ed = eb + ETOT + g * EPG;
  const int t = threadIdx.x;

  if (t < 64) deg_s[t] = 0;

  // ---- single global edge read -> registers (packed dst<<8|src)
  unsigned short epk[17];
  int nE = 0;
#pragma unroll
  for (int i = 0; i < 17; i++){
    int e = t + i * 512;
    if (e < EPG + 256){
      int sl, dl;
      if (e < EPG){ sl = es[e] & 255; dl = ed[e] & 255; }
      else { sl = dl = e - EPG; }
      epk[i] = (unsigned short)((dl << 8) | sl);
      nE = i + 1;
    }
  }

  // ---- xl = x@Wl + bl: thread t -> node t>>1, dim-half t&1, swizzled store
  {
    const int node = t >> 1, dh = t & 1;
    const int ks = (node >> 3) & 7;
    float xv[IND];
    const float* xr_ = x + (g * 256 + node) * IND;
#pragma unroll
    for (int k = 0; k < IND; k++) xv[k] = xr_[k];
#pragma unroll
    for (int ch = 0; ch < 4; ch++){
      f16x8 o;
#pragma unroll
      for (int j = 0; j < 8; j++){
        int dd = dh * 32 + ch * 8 + j;
        float a = bl[dd];
#pragma unroll
        for (int k = 0; k < IND; k++) a = fmaf(xv[k], Wl[k * HIDD + dd], a);
        o[j] = (f16)a;
      }
      int c = dh * 4 + ch;                         // logical chunk 0..7
      *(f16x8*)&xl_s[node * 72 + ((c ^ ks) * 8)] = o;
    }
  }
  __syncthreads();   // deg zero + xl_s visible

  // ---- single-pass CSR fill (from regs)
#pragma unroll
  for (int i = 0; i < 17; i++) if (i < nE){
    int dl = epk[i] >> 8, r = dl - lo;
    if ((unsigned)r < 64u){
      int p = atomicAdd(&deg_s[r], 1);
      if (p < DCAP) src_s[r * DCAP + p] = (unsigned char)(epk[i] & 255);
    }
  }
  __syncthreads();
  // ---- meta (degrees) + degree-sort permutation; dump CSR for gat2
  if (t < 64){
    int v = deg_s[t];
    meta[bid * 64 + t] = v;
    int r = 0;
#pragma unroll 8
    for (int j = 0; j < 64; j++){
      int dj = deg_s[j];
      r += (dj < v) || (dj == v && j < t);
    }
    perm[r] = (unsigned char)t;
  }
  {
    unsigned int* gsrc = (unsigned int*)(srcs + (size_t)bid * (64 * DCAP));
    for (int i = t; i < 64 * DCAP / 4; i += 512) gsrc[i] = src_su[i];
  }
  __syncthreads();

  // ---- 8 threads/dst (degree-sorted): my 8 xr dims, assemble 64 via shfl
  const int pairi = perm[t >> 3], sub = t & 7, ln = lo + pairi;
  f16x2 m[4], am[4];
  {
    float xv[IND];
    const float* xq = x + (g * 256 + ln) * IND;
#pragma unroll
    for (int k = 0; k < IND; k++) xv[k] = xq[k];
#pragma unroll
    for (int c = 0; c < 4; c++){
#pragma unroll
      for (int u = 0; u < 2; u++){
        int dd = sub * 8 + 2 * c + u;
        float a = br[dd];
#pragma unroll
        for (int k = 0; k < IND; k++) a = fmaf(xv[k], Wr[k * HIDD + dd], a);
        m[c][u] = (f16)a;
        am[c][u] = (f16)att[dd];
      }
    }
  }
  f16x2 xrh[32], atth[32];
  {
    const int base = (t & 63) & ~7;
#pragma unroll
    for (int ss = 0; ss < 8; ss++){
#pragma unroll
      for (int c = 0; c < 4; c++){
        xrh[ss * 4 + c] = shfl_h2(m[c], base + ss);
        atth[ss * 4 + c] = shfl_h2(am[c], base + ss);
      }
    }
  }

  // ---- scores + exp fused: edge-split (each thread every-8th edge, 64 dims)
  int dg = deg_s[pairi]; if (dg > DCAP) dg = DCAP;
  const int s0 = pairi * DCAP;
  const int sE = s0 + dg;
  float ssum = 0.f;
  for (int idx = s0 + sub; idx < sE; idx += 8){
    int sl = src_s[idx];
    int ksl = (sl >> 3) & 7;
    const f16x8* rp = (const f16x8*)&xl_s[(unsigned)sl * 72];
    float accs[4] = {0.f, 0.f, 0.f, 0.f};
#pragma unroll
    for (int blk = 0; blk < 8; blk++){
      f16x8 rv = rp[blk ^ ksl];
#pragma unroll
      for (int u = 0; u < 4; u++){
        f16x2 v = {rv[2 * u], rv[2 * u + 1]};
        v = v + xrh[blk * 4 + u];
        accs[u] = __builtin_amdgcn_fdot2(lrelu2(v), atth[blk * 4 + u], accs[u], false);
      }
    }
    float w = __expf((accs[0] + accs[1]) + (accs[2] + accs[3]));
    sc_h[idx] = (f16)w;
    ssum += w;
  }
  ssum += __shfl_xor(ssum, 1, 64);
  ssum += __shfl_xor(ssum, 2, 64);
  ssum += __shfl_xor(ssum, 4, 64);
  float inv = 1.f / ssum;
  // ---- aggregate alpha * xl[src], dim-split 8 ways (swizzled chunk reads)
  float acc[8];
#pragma unroll
  for (int c = 0; c < 8; c++) acc[c] = 0.f;
  {
    int sl = (s0 < sE) ? src_s[s0] : 0;
    f16x8 row = *(const f16x8*)&xl_s[(unsigned)sl * 72 + ((sub ^ ((sl >> 3) & 7)) * 8)];
    for (int idx = s0; idx < sE; idx++){
      int sln = (idx + 1 < sE) ? src_s[idx + 1] : 0;
      f16x8 rown = *(const f16x8*)&xl_s[(unsigned)sln * 72 + ((sub ^ ((sln >> 3) & 7)) * 8)];
      float w = (float)sc_h[idx];
#pragma unroll
      for (int c = 0; c < 8; c++) acc[c] = fmaf(w, (float)row[c], acc[c]);
      row = rown;
    }
  }
  f16x8 o;
#pragma unroll
  for (int c = 0; c < 8; c++)
    o[c] = (f16)fmaxf(acc[c] * inv + bias[sub * 8 + c], 0.f);
  *(f16x8*)(hmid + (size_t)(gs * 256 + ln) * 64 + sub * 8) = o;
}

// ---------------- GAT layer 2 + lin2 (fused, degree-sorted) ----------------
// Same grid/swizzle as gat1; fixed-bin CSR (base = dst*96) from gat1's dump.
__global__ __launch_bounds__(512, 4) void gat2(
    const int* __restrict__ meta, const unsigned char* __restrict__ srcs,
    const f16* __restrict__ hmid,
    const float* __restrict__ Wl, const float* __restrict__ Wr,
    const float* __restrict__ bl, const float* __restrict__ br,
    const float* __restrict__ att, const float* __restrict__ bias,
    f16* __restrict__ hout)
{
  __shared__ __align__(16) f16 xl_s[256 * 40];   // rows padded to 80B
  __shared__ __align__(16) f16 xr_s[64 * 40];
  __shared__ f16 sc_h[64 * DCAP];
  __shared__ unsigned int src_su[64 * DCAP / 4];
  __shared__ int deg_s[64];
  __shared__ unsigned char perm[64];
  unsigned char* src_s = (unsigned char*)src_su;

  const int bid = blockIdx.x;                    // same mapping as gat1
  const int gs = bid & 127, lo = (bid >> 7) * 64;
  const int t = threadIdx.x;

  // ---- CSR load (global -> LDS)
  if (t < 64) deg_s[t] = meta[bid * 64 + t];
  {
    const unsigned int* gsrc = (const unsigned int*)(srcs + (size_t)bid * (64 * DCAP));
    for (int i = t; i < 64 * DCAP / 4; i += 512) src_su[i] = gsrc[i];
  }

  // ---- in-block lin2 via MFMA
  {
    const int w = t >> 6, lane = t & 63;
    const int m = lane & 15, quad = lane >> 4;
    f16x8 a[2][2];
#pragma unroll
    for (int ti = 0; ti < 2; ti++){
      const f16* arow = hmid + (size_t)(gs * 256 + (2 * w + ti) * 16 + m) * 64;
      a[ti][0] = *(const f16x8*)(arow + quad * 8);
      a[ti][1] = *(const f16x8*)(arow + 32 + quad * 8);
    }
#pragma unroll
    for (int H = 0; H < 2; H++){
      const int n = H * 16 + m;
      f16x8 b0, b1;
#pragma unroll
      for (int j = 0; j < 8; j++){
        b0[j] = (f16)Wl[(quad * 8 + j) * 32 + n];
        b1[j] = (f16)Wl[(32 + quad * 8 + j) * 32 + n];
      }
      const float bv = bl[n];
#pragma unroll
      for (int ti = 0; ti < 2; ti++){
        f32x4 acc = {0.f, 0.f, 0.f, 0.f};
        acc = __builtin_amdgcn_mfma_f32_16x16x32_f16(a[ti][0], b0, acc, 0, 0, 0);
        acc = __builtin_amdgcn_mfma_f32_16x16x32_f16(a[ti][1], b1, acc, 0, 0, 0);
#pragma unroll
        for (int r = 0; r < 4; r++)
          xl_s[((2 * w + ti) * 16 + quad * 4 + r) * 40 + n] = (f16)(acc[r] + bv);
      }
    }
    if (w < 4){
      const f16* arow = hmid + (size_t)(gs * 256 + lo + w * 16 + m) * 64;
      f16x8 c0 = *(const f16x8*)(arow + quad * 8);
      f16x8 c1 = *(const f16x8*)(arow + 32 + quad * 8);
#pragma unroll
      for (int H = 0; H < 2; H++){
        const int n = H * 16 + m;
        f16x8 b0, b1;
#pragma unroll
        for (int j = 0; j < 8; j++){
          b0[j] = (f16)Wr[(quad * 8 + j) * 32 + n];
          b1[j] = (f16)Wr[(32 + quad * 8 + j) * 32 + n];
        }
        const float bv = br[n];
        f32x4 acc = {0.f, 0.f, 0.f, 0.f};
        acc = __builtin_amdgcn_mfma_f32_16x16x32_f16(c0, b0, acc, 0, 0, 0);
        acc = __builtin_amdgcn_mfma_f32_16x16x32_f16(c1, b1, acc, 0, 0, 0);
#pragma unroll
        for (int r = 0; r < 4; r++)
          xr_s[(w * 16 + quad * 4 + r) * 40 + n] = (f16)(acc[r] + bv);
      }
    }
  }
  __syncthreads();
  // ---- degree-sort permutation
  if (t < 64){
    int v = deg_s[t], r = 0;
#pragma unroll 8
    for (int j = 0; j < 64; j++){
      int dj = deg_s[j];
      r += (dj < v) || (dj == v && j < t);
    }
    perm[r] = (unsigned char)t;
  }
  __syncthreads();

  // ---- 8 threads/dst (sorted): full 32-dim xr + att in regs
  const int pairi = perm[t >> 3], sub = t & 7, ln = lo + pairi;
  f16x2 xrh[16], atth[16];
  {
    const f16x8* xrp = (const f16x8*)&xr_s[pairi * 40];
#pragma unroll
    for (int q = 0; q < 4; q++){
      f16x8 v = xrp[q];
#pragma unroll
      for (int u = 0; u < 4; u++){
        xrh[q * 4 + u][0] = v[2 * u];
        xrh[q * 4 + u][1] = v[2 * u + 1];
      }
    }
#pragma unroll
    for (int i = 0; i < 16; i++){
      atth[i][0] = (f16)att[2 * i];
      atth[i][1] = (f16)att[2 * i + 1];
    }
  }

  // ---- scores + exp fused: edge-split
  int dg = deg_s[pairi]; if (dg > DCAP) dg = DCAP;
  const int s0 = pairi * DCAP;
  const int sE = s0 + dg;
  float ssum = 0.f;
  for (int idx = s0 + sub; idx < sE; idx += 8){
    int sl = src_s[idx];
    const f16x8* rp = (const f16x8*)&xl_s[(unsigned)sl * 40];
    float accs[4] = {0.f, 0.f, 0.f, 0.f};
#pragma unroll
    for (int blk = 0; blk < 4; blk++){
      f16x8 rv = rp[blk];
#pragma unroll
      for (int u = 0; u < 4; u++){
        f16x2 v = {rv[2 * u], rv[2 * u + 1]};
        v = v + xrh[blk * 4 + u];
        accs[u] = __builtin_amdgcn_fdot2(lrelu2(v), atth[blk * 4 + u], accs[u], false);
      }
    }
    float w = __expf((accs[0] + accs[1]) + (accs[2] + accs[3]));
    sc_h[idx] = (f16)w;
    ssum += w;
  }
  ssum += __shfl_xor(ssum, 1, 64);
  ssum += __shfl_xor(ssum, 2, 64);
  ssum += __shfl_xor(ssum, 4, 64);
  float inv = 1.f / ssum;

  float acc[4];
#pragma unroll
  for (int c = 0; c < 4; c++) acc[c] = 0.f;
  {
    int sl = (s0 < sE) ? src_s[s0] : 0;
    f16x4 row = *(const f16x4*)&xl_s[(unsigned)sl * 40 + sub * 4];
    for (int idx = s0; idx < sE; idx++){
      int sln = (idx + 1 < sE) ? src_s[idx + 1] : 0;
      f16x4 rown = *(const f16x4*)&xl_s[(unsigned)sln * 40 + sub * 4];
      float w = (float)sc_h[idx];
#pragma unroll
      for (int c = 0; c < 4; c++) acc[c] = fmaf(w, (float)row[c], acc[c]);
      row = rown;
    }
  }
  f16x4 o;
#pragma unroll
  for (int c = 0; c < 4; c++)
    o[c] = (f16)(acc[c] * inv + bias[sub * 4 + c]);
  *(f16x4*)(hout + (size_t)(gs * 256 + ln) * 32 + sub * 4) = o;
}

// ---------------- sinkk: MFMA sim (in regs) + stats + histogram Sinkhorn ---
__global__ __launch_bounds__(1024) void sinkk(
    const f16* __restrict__ H,
    const float* __restrict__ gamma, const float* __restrict__ beta,
    float* __restrict__ res)
{
  __shared__ float rb[16];
  __shared__ unsigned int hist[8192];
  const int b = blockIdx.x, t = threadIdx.x;
  const int w = t >> 6, lane = t & 63;
  const int m = lane & 15, quad = lane >> 4;

  const f16* h1 = H + (size_t)b * 256 * 32;
  const f16* h2 = H + (size_t)(64 + b) * 256 * 32;

  f16x8 av = *(const f16x8*)(h1 + (size_t)(w * 16 + m) * 32 + quad * 8);
  f32x4 c[16];
#pragma unroll
  for (int j = 0; j < 16; j++){
    f16x8 bv = *(const f16x8*)(h2 + (size_t)(j * 16 + m) * 32 + quad * 8);
    f32x4 z = {0.f, 0.f, 0.f, 0.f};
    c[j] = __builtin_amdgcn_mfma_f32_16x16x32_f16(av, bv, z, 0, 0, 0);
  }

  float sm = 0.f, s2 = 0.f, mn = 3.0e38f, mx = -3.0e38f;
#pragma unroll
  for (int j = 0; j < 16; j++)
#pragma unroll
    for (int r = 0; r < 4; r++){
      float s = c[j][r];
      sm += s; s2 = fmaf(s, s, s2);
      mn = fminf(mn, s); mx = fmaxf(mx, s);
    }
  sm = bsum16(sm, rb);
  s2 = bsum16(s2, rb);
  mn = bmin16(mn, rb);
  mx = bmax16(mx, rb);

  const float mu = sm * (1.f / 65536.f);
  const float var = s2 * (1.f / 65536.f) - mu * mu;
  const float a = gamma[0] * rsqrtf(var + 1e-5f);
  const float cc = beta[0] - a * mu;
  float mnn = a * mn + cc, mxn = a * mx + cc;
  if (a < 0.f){ float tmp = mnn; mnn = mxn; mxn = tmp; }
  const float al = 2.f * a;
  const float be = 2.f * cc - mnn - mxn;
  const float R = fmaxf(mxn - mnn, 1e-12f);       // z in [-R, R]
  const float binscale = 4096.f / R;

  for (int i = t; i < 8192; i += 1024) hist[i] = 0u;
  __syncthreads();
#pragma unroll
  for (int j = 0; j < 16; j++)
#pragma unroll
    for (int r = 0; r < 4; r++){
      float z = fmaf(al, c[j][r], be);
      int bi = (int)fmaf(z, binscale, 4096.f);
      bi = min(max(bi, 0), 8191);
      atomicAdd(&hist[bi], 1u);
    }
  __syncthreads();

  const float wbin = R * (1.f / 4096.f);
  float ebs[8], cnts[8];
#pragma unroll
  for (int j = 0; j < 8; j++){
    float zc = fmaf((float)(t * 8 + j) + 0.5f, wbin, -R);
    ebs[j] = __expf(-zc);
    cnts[j] = (float)hist[t * 8 + j];
  }

  float D = 0.f, S = 256.f, eD = 1.f;
  for (int p = 0; p < 5; p++){
    float loc = 0.f;
#pragma unroll
    for (int j = 0; j < 8; j++)
      loc += cnts[j] / (1.f + ebs[j] * eD);
    S = bsum16(loc, rb);
    if (p < 4){
      D += -5.5412635f /* log(256/65280) */ + __logf(65536.f - S) - __logf(S);
      eD = __expf(-D);
    }
  }
  if (t == 0){
    res[b * 4 + 0] = al;
    res[b * 4 + 1] = be + D;
    res[b * 4 + 2] = 256.f / S;
  }
}

// ---------------- outk: MFMA sim quarter + sigmoid + write, full GPU -------
__global__ __launch_bounds__(1024) void outk(
    const f16* __restrict__ H, const float* __restrict__ res,
    float* __restrict__ out)
{
  const int b = blockIdx.x & 63, q = blockIdx.x >> 6, t = threadIdx.x;
  const int w = t >> 6, lane = t & 63;
  const int m = lane & 15, quad = lane >> 4;
  const int rowT = q * 64 + (w & 3) * 16;
  const int colB = (w >> 2) * 64;

  const float al = res[b * 4 + 0];
  const float beD = res[b * 4 + 1];
  const float scale = res[b * 4 + 2];

  const f16* h1 = H + (size_t)b * 256 * 32;
  const f16* h2 = H + (size_t)(64 + b) * 256 * 32;

  f16x8 av = *(const f16x8*)(h1 + (size_t)(rowT + m) * 32 + quad * 8);
  float* ob = out + (size_t)b * 65536;
#pragma unroll
  for (int jj = 0; jj < 4; jj++){
    f16x8 bv = *(const f16x8*)(h2 + (size_t)(colB + jj * 16 + m) * 32 + quad * 8);
    f32x4 z = {0.f, 0.f, 0.f, 0.f};
    f32x4 c = __builtin_amdgcn_mfma_f32_16x16x32_f16(av, bv, z, 0, 0, 0);
#pragma unroll
    for (int r = 0; r < 4; r++){
      float zz = fmaf(al, c[r], beD);
      float v = fminf(scale / (1.f + __expf(-zz)), 1.f);
      ob[(rowT + quad * 4 + r) * 256 + colB + jj * 16 + m] = v;
    }
  }
}

extern "C" void kernel_launch(void* const* d_in, const int* in_sizes, int n_in,
                              void* d_out, int out_size, void* d_ws, size_t ws_size,
                              hipStream_t stream)
{
  const float* x1   = (const float*)d_in[0];
  const float* x2   = (const float*)d_in[1];
  const int*   e1   = (const int*)d_in[2];
  const int*   e2   = (const int*)d_in[3];
  const float* Wl1  = (const float*)d_in[4];
  const float* Wr1  = (const float*)d_in[5];
  const float* bl1  = (const float*)d_in[6];
  const float* br1  = (const float*)d_in[7];
  const float* att1 = (const float*)d_in[8];
  const float* bias1= (const float*)d_in[9];
  const float* Wl2  = (const float*)d_in[10];
  const float* Wr2  = (const float*)d_in[11];
  const float* bl2  = (const float*)d_in[12];
  const float* br2  = (const float*)d_in[13];
  const float* att2 = (const float*)d_in[14];
  const float* bias2= (const float*)d_in[15];
  const float* gamma= (const float*)d_in[16];
  const float* beta = (const float*)d_in[17];

  // ws (~9.5 MB): hfin [0,2M); hmid [2M,6M); meta [6M,+128K);
  // srcs [6M+128K, +3M); res [9.5M,+1K).
  char* ws = (char*)d_ws;
  f16* hfin = (f16*)ws;
  f16* hmid = (f16*)(ws + (size_t)2 * 1024 * 1024);
  int* meta = (int*)(ws + (size_t)6 * 1024 * 1024);
  unsigned char* srcs = (unsigned char*)(ws + (size_t)6 * 1024 * 1024 + 512 * 64 * 4);
  float* res = (float*)(ws + (size_t)9 * 1024 * 1024 + 512 * 1024);
  float* out = (float*)d_out;

  gat1<<<512, 512, 0, stream>>>(x1, x2, e1, e2, Wl1, Wr1, bl1, br1, att1, bias1,
                                hmid, meta, srcs);
  gat2<<<512, 512, 0, stream>>>(meta, srcs, hmid, Wl2, Wr2, bl2, br2, att2, bias2, hfin);
  sinkk<<<64, 1024, 0, stream>>>(hfin, gamma, beta, res);
  outk<<<256, 1024, 0, stream>>>(hfin, res, out);
}